// Round 8
// baseline (579.355 us; speedup 1.0000x reference)
//
#include <hip/hip_runtime.h>
#include <hip/hip_bf16.h>
#include <stdint.h>

typedef __hip_bfloat16 bf16;
typedef __attribute__((ext_vector_type(8))) short bf16x8_t;
typedef __attribute__((ext_vector_type(4))) float f32x4_t;
typedef __attribute__((ext_vector_type(16))) float f32x16_t;
typedef __attribute__((ext_vector_type(2))) unsigned int u32x2_t;

#define B_ 4
#define T_ 2048
#define D_ 1024
#define H_ 16
#define HS_ 64
#define QKV_LD 3072

// ---------------------------------------------------------------- helpers
__device__ __forceinline__ void gload_lds16(const void* g, void* l) {
    __builtin_amdgcn_global_load_lds(
        (const __attribute__((address_space(1))) unsigned int*)g,
        (__attribute__((address_space(3))) unsigned int*)l, 16, 0, 0);
}

__device__ __forceinline__ bf16x8_t ldsv8(const bf16* p) {
    return *(const bf16x8_t*)p;
}

__device__ __forceinline__ unsigned pack2(float a, float b) {
    union { bf16 h[2]; unsigned u; } t;
    t.h[0] = __float2bfloat16(a);
    t.h[1] = __float2bfloat16(b);
    return t.u;
}

__device__ __forceinline__ float tmax16(const f32x16_t& s) {
    float a = fmaxf(s[0], s[8]),  b = fmaxf(s[1], s[9]);
    float c = fmaxf(s[2], s[10]), d = fmaxf(s[3], s[11]);
    float e = fmaxf(s[4], s[12]), f = fmaxf(s[5], s[13]);
    float g = fmaxf(s[6], s[14]), h = fmaxf(s[7], s[15]);
    a = fmaxf(a, e); b = fmaxf(b, f); c = fmaxf(c, g); d = fmaxf(d, h);
    return fmaxf(fmaxf(a, c), fmaxf(b, d));
}

__device__ __forceinline__ float tsum16(const f32x16_t& s) {
    float a = s[0] + s[8],  b = s[1] + s[9];
    float c = s[2] + s[10], d = s[3] + s[11];
    float e = s[4] + s[12], f = s[5] + s[13];
    float g = s[6] + s[14], h = s[7] + s[15];
    a += e; b += f; c += g; d += h;
    return (a + c) + (b + d);
}

// ---------------------------------------------------------------- fused weight transpose fp32->bf16
// all six weights in one launch: blocks [0,4096) wq/wk/wv/wo; [4096,8192) w1; [8192,12288) w2
__global__ __launch_bounds__(256) void transpose_all(
    const float* wq, const float* wk, const float* wv, const float* wo,
    const float* w1, const float* w2,
    bf16* wqkvT, bf16* woT, bf16* w1T, bf16* w2T)
{
    __shared__ float tile[32][33];
    int blk = blockIdx.x;
    const float* W; bf16* WT; int K, N;
    if (blk < 4096) {
        const int which = blk >> 10; blk &= 1023;
        W  = which == 0 ? wq : which == 1 ? wk : which == 2 ? wv : wo;
        WT = which == 3 ? woT : wqkvT + (size_t)which * 1024 * 1024;
        K = 1024; N = 1024;
    } else if (blk < 8192) {
        blk -= 4096; W = w1; WT = w1T; K = 1024; N = 4096;
    } else {
        blk -= 8192; W = w2; WT = w2T; K = 4096; N = 1024;
    }
    const int nbx = N >> 5;
    const int bx = blk % nbx;
    const int by = blk / nbx;
    const int n0 = bx << 5, k0 = by << 5;
    const int tx = threadIdx.x & 31, ty = threadIdx.x >> 5;
#pragma unroll
    for (int i = 0; i < 32; i += 8)
        tile[ty + i][tx] = W[(long)(k0 + ty + i) * N + n0 + tx];
    __syncthreads();
#pragma unroll
    for (int i = 0; i < 32; i += 8)
        WT[(long)(n0 + ty + i) * K + k0 + tx] = __float2bfloat16(tile[tx][ty + i]);
}

// ---------------------------------------------------------------- per-head V transpose (bf16)
__global__ __launch_bounds__(256) void vhead_transpose(
    const bf16* __restrict__ QKV, bf16* __restrict__ VT)
{
    __shared__ bf16 tile[32][33];
    int idx = blockIdx.x;
    const int tt  = idx & 63;   idx >>= 6;
    const int hst = idx & 1;    idx >>= 1;
    const int bh  = idx;
    const int b = bh >> 4, h = bh & 15;
    const int tx = threadIdx.x & 31, ty = threadIdx.x >> 5;
    const long vrow = (long)b * T_ + tt * 32;
    const int  vcol = 2048 + h * HS_ + hst * 32;
#pragma unroll
    for (int i = 0; i < 32; i += 8)
        tile[ty + i][tx] = QKV[(vrow + ty + i) * QKV_LD + vcol + tx];
    __syncthreads();
    const long orow = (long)bh * HS_ + hst * 32;
#pragma unroll
    for (int i = 0; i < 32; i += 8)
        VT[(orow + ty + i) * T_ + tt * 32 + tx] = tile[tx][ty + i];
}

// ---------------------------------------------------------------- LayerNorm (fp32 in -> bf16 out)
__global__ __launch_bounds__(256) void ln_k(
    const float* __restrict__ x, const float* __restrict__ g,
    const float* __restrict__ be, bf16* __restrict__ out)
{
    const long row = blockIdx.x;
    const int t = threadIdx.x;
    const float4 v = ((const float4*)(x + row * D_))[t];
    float s  = v.x + v.y + v.z + v.w;
    float s2 = v.x * v.x + v.y * v.y + v.z * v.z + v.w * v.w;
#pragma unroll
    for (int m = 1; m < 64; m <<= 1) {
        s  += __shfl_xor(s, m, 64);
        s2 += __shfl_xor(s2, m, 64);
    }
    __shared__ float red[8];
    const int wv = t >> 6, ln = t & 63;
    if (ln == 0) { red[wv] = s; red[4 + wv] = s2; }
    __syncthreads();
    s  = red[0] + red[1] + red[2] + red[3];
    s2 = red[4] + red[5] + red[6] + red[7];
    const float mu  = s * (1.f / (float)D_);
    const float var = s2 * (1.f / (float)D_) - mu * mu;
    const float rs  = rsqrtf(var + 1e-5f);
    const float4 gv = ((const float4*)g)[t];
    const float4 bv = ((const float4*)be)[t];
    union { bf16 h[4]; short4 s4; } u;
    u.h[0] = __float2bfloat16((v.x - mu) * rs * gv.x + bv.x);
    u.h[1] = __float2bfloat16((v.y - mu) * rs * gv.y + bv.y);
    u.h[2] = __float2bfloat16((v.z - mu) * rs * gv.z + bv.z);
    u.h[3] = __float2bfloat16((v.w - mu) * rs * gv.w + bv.w);
    ((short4*)(out + row * D_))[t] = u.s4;
}

// ---------------------------------------------------------------- GEMM v2b: 256x128 tile, 8 waves,
// BK=64 dbuf, counted vmcnt, split-lgkm two-stage MFMA (ks0 hides ks1 reads; ks1 hides stage).
template<int HAS_BIAS, int RELU, int HAS_RES, int OUT_BF16>
__global__ __launch_bounds__(512, 1) void gemm2(
    const bf16* __restrict__ A, const bf16* __restrict__ BT,
    const float* __restrict__ bias, const float* __restrict__ res,
    void* __restrict__ Cout, int M, int N, int K)
{
    __shared__ bf16 As[2][256 * 64];
    __shared__ bf16 Bs[2][128 * 64];
    const int tid  = threadIdx.x;
    const int w    = tid >> 6;
    const int lane = tid & 63;
    const int wm = w >> 1, wn = w & 1;
    const int nbn = N >> 7;
    const int cpx = gridDim.x >> 3;
    const int bid = (blockIdx.x & 7) * cpx + (blockIdx.x >> 3);
    const int bm = bid / nbn, bn = bid % nbn;
    const int row0 = bm << 8, col0 = bn << 7;

    const bf16* aS0; const bf16* aS1; const bf16* aS2; const bf16* aS3;
    const bf16* bS0; const bf16* bS1;
    {
        int f0 = tid,        r0 = f0 >> 3, c0 = ((f0 & 7) ^ (r0 & 7)) << 3;
        int f1 = 512 + tid,  r1 = f1 >> 3, c1 = ((f1 & 7) ^ (r1 & 7)) << 3;
        int f2 = 1024 + tid, r2 = f2 >> 3, c2 = ((f2 & 7) ^ (r2 & 7)) << 3;
        int f3 = 1536 + tid, r3 = f3 >> 3, c3 = ((f3 & 7) ^ (r3 & 7)) << 3;
        aS0 = A + (long)(row0 + r0) * K + c0;
        aS1 = A + (long)(row0 + r1) * K + c1;
        aS2 = A + (long)(row0 + r2) * K + c2;
        aS3 = A + (long)(row0 + r3) * K + c3;
        bS0 = BT + (long)(col0 + r0) * K + c0;
        bS1 = BT + (long)(col0 + r1) * K + c1;
    }
    const int wbase = w * 64;

#define STAGE2(buf, kt) do {                                             \
        const long ko_ = (long)(kt) * 64;                                \
        gload_lds16(aS0 + ko_, &As[buf][(0 * 512 + wbase) * 8]);         \
        gload_lds16(aS1 + ko_, &As[buf][(1 * 512 + wbase) * 8]);         \
        gload_lds16(aS2 + ko_, &As[buf][(2 * 512 + wbase) * 8]);         \
        gload_lds16(aS3 + ko_, &As[buf][(3 * 512 + wbase) * 8]);         \
        gload_lds16(bS0 + ko_, &Bs[buf][(0 * 512 + wbase) * 8]);         \
        gload_lds16(bS1 + ko_, &Bs[buf][(1 * 512 + wbase) * 8]);         \
    } while (0)

    f32x4_t acc[4][4] = {};
    const int fr = lane & 15;
    const int fq = lane >> 4;
    const int nt = K >> 6;

    STAGE2(0, 0);
    STAGE2(1, 1);

    for (int t = 0; t < nt; ++t) {
        const int cur = t & 1;
        if (t < nt - 1) asm volatile("s_waitcnt vmcnt(6)" ::: "memory");
        else            asm volatile("s_waitcnt vmcnt(0)" ::: "memory");
        __builtin_amdgcn_s_barrier();

        bf16x8_t a0[4], b0[4], a1[4], b1[4];
#pragma unroll
        for (int m = 0; m < 4; ++m) {
            const int r = wm * 64 + m * 16 + fr;
            a0[m] = ldsv8(&As[cur][r * 64 + ((fq ^ (r & 7)) << 3)]);
        }
#pragma unroll
        for (int n = 0; n < 4; ++n) {
            const int r = wn * 64 + n * 16 + fr;
            b0[n] = ldsv8(&Bs[cur][r * 64 + ((fq ^ (r & 7)) << 3)]);
        }
        __builtin_amdgcn_sched_barrier(0);   // pin group order for lgkmcnt(8)
#pragma unroll
        for (int m = 0; m < 4; ++m) {
            const int r = wm * 64 + m * 16 + fr;
            a1[m] = ldsv8(&As[cur][r * 64 + (((4 + fq) ^ (r & 7)) << 3)]);
        }
#pragma unroll
        for (int n = 0; n < 4; ++n) {
            const int r = wn * 64 + n * 16 + fr;
            b1[n] = ldsv8(&Bs[cur][r * 64 + (((4 + fq) ^ (r & 7)) << 3)]);
        }
        asm volatile("s_waitcnt lgkmcnt(8)" ::: "memory");   // ks0 group landed
        __builtin_amdgcn_sched_barrier(0);
        __builtin_amdgcn_s_setprio(1);
#pragma unroll
        for (int m = 0; m < 4; ++m)
#pragma unroll
            for (int n = 0; n < 4; ++n)
                acc[m][n] = __builtin_amdgcn_mfma_f32_16x16x32_bf16(a0[m], b0[n], acc[m][n], 0, 0, 0);
        __builtin_amdgcn_s_setprio(0);
        asm volatile("s_waitcnt lgkmcnt(0)" ::: "memory");   // all reads done before overwrite
        __builtin_amdgcn_sched_barrier(0);
        __builtin_amdgcn_s_barrier();
        if (t + 2 < nt) STAGE2(cur, t + 2);
        __builtin_amdgcn_s_setprio(1);
#pragma unroll
        for (int m = 0; m < 4; ++m)
#pragma unroll
            for (int n = 0; n < 4; ++n)
                acc[m][n] = __builtin_amdgcn_mfma_f32_16x16x32_bf16(a1[m], b1[n], acc[m][n], 0, 0, 0);
        __builtin_amdgcn_s_setprio(0);
    }
#undef STAGE2

    const int orow = fq << 2;
#pragma unroll
    for (int m = 0; m < 4; ++m) {
        const int rbase = row0 + wm * 64 + m * 16 + orow;
#pragma unroll
        for (int n = 0; n < 4; ++n) {
            const int c = col0 + wn * 64 + n * 16 + fr;
            float bv = 0.f;
            if (HAS_BIAS) bv = bias[c];
#pragma unroll
            for (int r = 0; r < 4; ++r) {
                float v = acc[m][n][r] + bv;
                if (RELU) v = fmaxf(v, 0.f);
                if (HAS_RES) v += res[(long)(rbase + r) * N + c];
                if (OUT_BF16)
                    ((bf16*)Cout)[(long)(rbase + r) * N + c] = __float2bfloat16(v);
                else
                    ((float*)Cout)[(long)(rbase + r) * N + c] = v;
            }
        }
    }
}

// ---------------------------------------------------------------- GEMM v3b: 256x256, 8 waves,
// 4-phase/K-tile, counted vmcnt, register read-ahead (P2-P4 operand reads hidden under
// previous phase's MFMA), full-coverage swizzle (r ^ r>>2)&3.
template<int HAS_BIAS, int RELU, int HAS_RES, int OUT_BF16>
__global__ __launch_bounds__(512, 1) void gemm8(
    const bf16* __restrict__ A, const bf16* __restrict__ BT,
    const float* __restrict__ bias, const float* __restrict__ res,
    void* __restrict__ Cout, int M, int N, int K)
{
    __shared__ bf16 As[2][2][256 * 32];
    __shared__ bf16 Bs[2][2][256 * 32];

    const int tid  = threadIdx.x;
    const int w    = tid >> 6;
    const int lane = tid & 63;
    const int wm = w >> 2, wn = w & 3;
    const int nbn = N >> 8;
    const int cpx = gridDim.x >> 3;
    const int bid = (blockIdx.x & 7) * cpx + (blockIdx.x >> 3);
    const int bm = bid / nbn, bn = bid % nbn;
    const int row0 = bm << 8, col0 = bn << 8;

    const int r0s = tid >> 2;
    const int c0s = (((tid & 3) ^ ((r0s ^ (r0s >> 2)) & 3)) << 3);
    const bf16* aU0 = A  + (long)(row0 + r0s) * K + c0s;
    const bf16* aU1 = aU0 + (long)128 * K;
    const bf16* bU0 = BT + (long)(col0 + r0s) * K + c0s;
    const bf16* bU1 = bU0 + (long)128 * K;
    const int wb8 = w * 512;

#define STAGE_A8(buf, kh, kt) do {                                        \
        const long ko_ = (long)(kt) * 64 + (kh) * 32;                     \
        gload_lds16(aU0 + ko_, &As[buf][kh][wb8]);                        \
        gload_lds16(aU1 + ko_, &As[buf][kh][4096 + wb8]);                 \
    } while (0)
#define STAGE_B8(buf, kh, kt) do {                                        \
        const long ko_ = (long)(kt) * 64 + (kh) * 32;                     \
        gload_lds16(bU0 + ko_, &Bs[buf][kh][wb8]);                        \
        gload_lds16(bU1 + ko_, &Bs[buf][kh][4096 + wb8]);                 \
    } while (0)

    f32x4_t acc[8][4] = {};
    bf16x8_t afA[8], afB[8], b01[2], b23[2], b01b[2], b23b[2];
    const int fr = lane & 15;
    const int fq = lane >> 4;
    const int nt = K >> 6;

#define SWZ8(rr) ((fq ^ ((rr ^ (rr >> 2)) & 3)) << 3)
#define RD_A8(dst, cur, ks) do { _Pragma("unroll")                         \
        for (int m = 0; m < 8; ++m) {                                      \
            const int rr = wm * 128 + m * 16 + fr;                         \
            dst[m] = ldsv8(&As[cur][ks][rr * 32 + SWZ8(rr)]);              \
        } } while (0)
#define RD_B8(dst, cur, ks, n0) do {                                       \
        { const int rr = wn * 64 + (n0) * 16 + fr;                         \
          dst[0] = ldsv8(&Bs[cur][ks][rr * 32 + SWZ8(rr)]); }              \
        { const int rr = wn * 64 + ((n0) + 1) * 16 + fr;                   \
          dst[1] = ldsv8(&Bs[cur][ks][rr * 32 + SWZ8(rr)]); }              \
    } while (0)
#define MM8(afx, bp, n0) do { _Pragma("unroll")                            \
        for (int m = 0; m < 8; ++m) {                                      \
            acc[m][n0]     = __builtin_amdgcn_mfma_f32_16x16x32_bf16(afx[m], bp[0], acc[m][n0],     0, 0, 0); \
            acc[m][(n0)+1] = __builtin_amdgcn_mfma_f32_16x16x32_bf16(afx[m], bp[1], acc[m][(n0)+1], 0, 0, 0); \
        } } while (0)
#define LGKM0_ do { asm volatile("s_waitcnt lgkmcnt(0)" ::: "memory");     \
                    __builtin_amdgcn_sched_barrier(0); } while (0)
#define SBAR_  __builtin_amdgcn_s_barrier()
#define PIN_   __builtin_amdgcn_sched_barrier(0)

    // prologue: stage tile 0
    STAGE_A8(0, 0, 0);
    STAGE_B8(0, 0, 0);
    STAGE_A8(0, 1, 0);
    STAGE_B8(0, 1, 0);
    asm volatile("s_waitcnt vmcnt(4)" ::: "memory");
    SBAR_;

    for (int t = 0; t < nt - 1; ++t) {
        const int cur = t & 1, nb = cur ^ 1;
        // P1: cold reads ks0; MFMA region reads b23 ahead
        RD_A8(afA, cur, 0); RD_B8(b01, cur, 0, 0);
        STAGE_A8(nb, 0, t + 1);
        SBAR_;
        LGKM0_;
        __builtin_amdgcn_s_setprio(1);
        RD_B8(b23, cur, 0, 2); PIN_;
        MM8(afA, b01, 0);
        __builtin_amdgcn_s_setprio(0);
        SBAR_;
        // P2: vm4 at opening legalizes khalf-1 reads inside MFMA region
        STAGE_B8(nb, 0, t + 1);
        asm volatile("s_waitcnt vmcnt(4)" ::: "memory");
        SBAR_;
        LGKM0_;
        __builtin_amdgcn_s_setprio(1);
        RD_A8(afB, cur, 1); RD_B8(b01b, cur, 1, 0); PIN_;
        MM8(afA, b23, 2);
        __builtin_amdgcn_s_setprio(0);
        SBAR_;
        // P3
        STAGE_A8(nb, 1, t + 1);
        SBAR_;
        LGKM0_;
        __builtin_amdgcn_s_setprio(1);
        RD_B8(b23b, cur, 1, 2); PIN_;
        MM8(afB, b01b, 0);
        __builtin_amdgcn_s_setprio(0);
        SBAR_;
        // P4: closing vm4 legalizes next tile's P1 reads
        STAGE_B8(nb, 1, t + 1);
        SBAR_;
        LGKM0_;
        __builtin_amdgcn_s_setprio(1);
        MM8(afB, b23b, 2);
        __builtin_amdgcn_s_setprio(0);
        asm volatile("s_waitcnt vmcnt(4)" ::: "memory");
        SBAR_;
    }
    {   // final tile: vm0 at P2 opening (no new stages to count against)
        const int cur = (nt - 1) & 1;
        RD_A8(afA, cur, 0); RD_B8(b01, cur, 0, 0);
        SBAR_;
        LGKM0_;
        __builtin_amdgcn_s_setprio(1);
        RD_B8(b23, cur, 0, 2); PIN_;
        MM8(afA, b01, 0);
        __builtin_amdgcn_s_setprio(0);
        SBAR_;
        asm volatile("s_waitcnt vmcnt(0)" ::: "memory");
        SBAR_;
        LGKM0_;
        __builtin_amdgcn_s_setprio(1);
        RD_A8(afB, cur, 1); RD_B8(b01b, cur, 1, 0); PIN_;
        MM8(afA, b23, 2);
        __builtin_amdgcn_s_setprio(0);
        SBAR_;
        SBAR_;
        LGKM0_;
        __builtin_amdgcn_s_setprio(1);
        RD_B8(b23b, cur, 1, 2); PIN_;
        MM8(afB, b01b, 0);
        __builtin_amdgcn_s_setprio(0);
        SBAR_;
        LGKM0_;
        MM8(afB, b23b, 2);
    }
#undef STAGE_A8
#undef STAGE_B8
#undef SWZ8
#undef RD_A8
#undef RD_B8
#undef MM8
#undef LGKM0_
#undef SBAR_
#undef PIN_

    const int orow = fq << 2;
#pragma unroll
    for (int m = 0; m < 8; ++m) {
        const int rbase = row0 + wm * 128 + m * 16 + orow;
#pragma unroll
        for (int n = 0; n < 4; ++n) {
            const int c = col0 + wn * 64 + n * 16 + fr;
            float bv = 0.f;
            if (HAS_BIAS) bv = bias[c];
#pragma unroll
            for (int r = 0; r < 4; ++r) {
                float v = acc[m][n][r] + bv;
                if (RELU) v = fmaxf(v, 0.f);
                if (HAS_RES) v += res[(long)(rbase + r) * N + c];
                if (OUT_BF16)
                    ((bf16*)Cout)[(long)(rbase + r) * N + c] = __float2bfloat16(v);
                else
                    ((float*)Cout)[(long)(rbase + r) * N + c] = v;
            }
        }
    }
}

// ---------------------------------------------------------------- attention: NQ q-tiles sharing
// one KV stream (shared K/V fragment loads), tree reductions, T13 defer-max, T5 setprio.
template<int NQ>
__device__ __forceinline__ void attn_tiles(
    const bf16* K_, const bf16* V_, const bf16x8_t (&qf)[2][4],
    f32x16_t (&oA)[2], f32x16_t (&oB)[2], float (&mOld)[2], float (&lSum)[2],
    int c, const int (&ctw)[2], const int (&qabs)[2],
    int w, int l31, int hi, int hi8, int swzk)
{
    const float kE  = 0.0450842200278f;   // (1/32) * log2(e)
    const float THR = 256.0f;             // defer-max threshold (e^8 bound)
    const bool two = (NQ == 2) ? true : !((c == ctw[0]) && !(w & 1));

    f32x16_t s0[NQ] = {}, s1[NQ] = {};

    __builtin_amdgcn_s_setprio(1);
#pragma unroll
    for (int s = 0; s < 4; ++s) {
        bf16x8_t kf = ldsv8(K_ + l31 * 64 + ((16 * s + hi8) ^ swzk));
#pragma unroll
        for (int qi = 0; qi < NQ; ++qi)
            s0[qi] = __builtin_amdgcn_mfma_f32_32x32x16_bf16(kf, qf[qi][s], s0[qi], 0, 0, 0);
    }
    if (two) {
#pragma unroll
        for (int s = 0; s < 4; ++s) {
            bf16x8_t kf = ldsv8(K_ + (32 + l31) * 64 + ((16 * s + hi8) ^ swzk));
#pragma unroll
            for (int qi = 0; qi < NQ; ++qi)
                s1[qi] = __builtin_amdgcn_mfma_f32_32x32x16_bf16(kf, qf[qi][s], s1[qi], 0, 0, 0);
        }
    }
    __builtin_amdgcn_s_setprio(0);

    // causal mask (generic element check; non-diag tiles skip entirely)
#pragma unroll
    for (int qi = 0; qi < NQ; ++qi) {
        if (c == ctw[qi]) {
            const int kb0 = c * 64 + 4 * hi;
#pragma unroll
            for (int r = 0; r < 16; ++r) {
                const int ko = (r & 3) + 8 * (r >> 2);
                if (kb0 + ko > qabs[qi]) s0[qi][r] = -1e30f;
                if (two) { if (kb0 + 32 + ko > qabs[qi]) s1[qi][r] = -1e30f; }
            }
        }
    }

    // online softmax per q-tile (lane-local rows; tree reductions)
#pragma unroll
    for (int qi = 0; qi < NQ; ++qi) {
        float rm = tmax16(s0[qi]);
        if (two) rm = fmaxf(rm, tmax16(s1[qi]));
        {
            u32x2_t rr = __builtin_amdgcn_permlane32_swap(
                __float_as_uint(rm), __float_as_uint(rm), false, false);
            rm = fmaxf(__uint_as_float(rr.x), __uint_as_float(rr.y));
        }
        if (!__all(rm <= mOld[qi] + THR)) {
            const float mN = fmaxf(mOld[qi], rm);
            const float corr = exp2f((mOld[qi] - mN) * kE);
#pragma unroll
            for (int r = 0; r < 16; ++r) { oA[qi][r] *= corr; oB[qi][r] *= corr; }
            lSum[qi] *= corr;
            mOld[qi] = mN;
        }
        const float nmk = -mOld[qi] * kE;
#pragma unroll
        for (int r = 0; r < 16; ++r) s0[qi][r] = exp2f(fmaf(s0[qi][r], kE, nmk));
        if (two) {
#pragma unroll
            for (int r = 0; r < 16; ++r) s1[qi][r] = exp2f(fmaf(s1[qi][r], kE, nmk));
        }
        float rs = tsum16(s0[qi]);
        if (two) rs += tsum16(s1[qi]);
        {
            u32x2_t rr = __builtin_amdgcn_permlane32_swap(
                __float_as_uint(rs), __float_as_uint(rs), false, false);
            rs = __uint_as_float(rr.x) + __uint_as_float(rr.y);
        }
        lSum[qi] += rs;
    }

    // pack P (T12): W[qi][slice], slices 0,1 from s0; 2,3 from s1
    union uW { unsigned u[4]; bf16x8_t v; };
    uW W[NQ][4];
#pragma unroll
    for (int qi = 0; qi < NQ; ++qi) {
        unsigned pk_[8];
#pragma unroll
        for (int i = 0; i < 8; ++i) pk_[i] = pack2(s0[qi][2 * i], s0[qi][2 * i + 1]);
        u32x2_t ra = __builtin_amdgcn_permlane32_swap(pk_[0], pk_[2], false, false);
        u32x2_t rb = __builtin_amdgcn_permlane32_swap(pk_[1], pk_[3], false, false);
        W[qi][0].u[0] = ra.x; W[qi][0].u[1] = rb.x; W[qi][0].u[2] = ra.y; W[qi][0].u[3] = rb.y;
        u32x2_t rc = __builtin_amdgcn_permlane32_swap(pk_[4], pk_[6], false, false);
        u32x2_t rd = __builtin_amdgcn_permlane32_swap(pk_[5], pk_[7], false, false);
        W[qi][1].u[0] = rc.x; W[qi][1].u[1] = rd.x; W[qi][1].u[2] = rc.y; W[qi][1].u[3] = rd.y;
        if (two) {
#pragma unroll
            for (int i = 0; i < 8; ++i) pk_[i] = pack2(s1[qi][2 * i], s1[qi][2 * i + 1]);
            u32x2_t re = __builtin_amdgcn_permlane32_swap(pk_[0], pk_[2], false, false);
            u32x2_t rf = __builtin_amdgcn_permlane32_swap(pk_[1], pk_[3], false, false);
            W[qi][2].u[0] = re.x; W[qi][2].u[1] = rf.x; W[qi][2].u[2] = re.y; W[qi][2].u[3] = rf.y;
            u32x2_t rg = __builtin_amdgcn_permlane32_swap(pk_[4], pk_[6], false, false);
            u32x2_t rh = __builtin_amdgcn_permlane32_swap(pk_[5], pk_[7], false, false);
            W[qi][3].u[0] = rg.x; W[qi][3].u[1] = rh.x; W[qi][3].u[2] = rg.y; W[qi][3].u[3] = rh.y;
        }
    }

    // O^T += V^T P  (shared V fragment loads across q-tiles)
    __builtin_amdgcn_s_setprio(1);
#pragma unroll
    for (int sl = 0; sl < 4; ++sl) {
        if (sl < 2 || two) {
            const int kcol = 16 * sl + hi8;
            bf16x8_t vf0 = ldsv8(V_ + l31 * 64 + (kcol ^ swzk));
            bf16x8_t vf1 = ldsv8(V_ + (32 + l31) * 64 + (kcol ^ swzk));
#pragma unroll
            for (int qi = 0; qi < NQ; ++qi) {
                oA[qi] = __builtin_amdgcn_mfma_f32_32x32x16_bf16(vf0, W[qi][sl].v, oA[qi], 0, 0, 0);
                oB[qi] = __builtin_amdgcn_mfma_f32_32x32x16_bf16(vf1, W[qi][sl].v, oB[qi], 0, 0, 0);
            }
        }
    }
    __builtin_amdgcn_s_setprio(0);
}

// flash attention (causal): complementary q-tile pairing (qi 0 = qHi, 1 = qLo),
// grid (4,64) = 256 blocks = 1/CU, perfectly balanced (36 kv-tile computes/block).
__global__ __launch_bounds__(512, 1) void attn_flash(
    const bf16* __restrict__ QKV, const bf16* __restrict__ VT,
    bf16* __restrict__ O)
{
    __shared__ bf16 Ks[2][64 * 64];
    __shared__ bf16 Vs[2][64 * 64];

    const int tid = threadIdx.x;
    const int w   = tid >> 6;
    const int ln  = tid & 63;
    const int l31 = ln & 31;
    const int hi  = ln >> 5;
    const int hi8 = hi << 3;

    const int qLo = blockIdx.x;
    const int qHi = 7 - qLo;
    const int bh = blockIdx.y;
    const long rowBase = (long)(bh >> 4) * T_;
    const int colBase = (bh & 15) * HS_;

    int qabs[2], ctw[2];
    qabs[0] = qHi * 256 + w * 32 + l31;
    qabs[1] = qLo * 256 + w * 32 + l31;
    ctw[0]  = qHi * 4 + (w >> 1);
    ctw[1]  = qLo * 4 + (w >> 1);
    const int ctb = qHi * 4 + 3;

    bf16x8_t qf[2][4];
    {
        const bf16* qp0 = QKV + (rowBase + qabs[0]) * QKV_LD + colBase + hi8;
        const bf16* qp1 = QKV + (rowBase + qabs[1]) * QKV_LD + colBase + hi8;
#pragma unroll
        for (int s = 0; s < 4; ++s) {
            qf[0][s] = *(const bf16x8_t*)(qp0 + 16 * s);
            qf[1][s] = *(const bf16x8_t*)(qp1 + 16 * s);
        }
    }

    f32x16_t oA[2] = {}, oB[2] = {};
    float mOld[2] = { -1e30f, -1e30f }, lSum[2] = { 0.f, 0.f };

    const int srow = tid >> 3;
    const int schunk = (((tid & 7) ^ (srow & 7)) << 3);
    const bf16* kSrc = QKV + (rowBase + srow) * QKV_LD + 1024 + colBase + schunk;
    const bf16* vSrc = VT + ((long)bh * HS_ + srow) * T_ + schunk;

    gload_lds16(kSrc, &Ks[0][w * 512]);
    gload_lds16(vSrc, &Vs[0][w * 512]);

    const int swzk = (l31 & 7) << 3;

    for (int c = 0; c <= ctb; ++c) {
        const int cur = c & 1;
        __syncthreads();

        if (c < ctb) {
            gload_lds16(kSrc + (long)(c + 1) * 64 * QKV_LD, &Ks[cur ^ 1][w * 512]);
            gload_lds16(vSrc + (c + 1) * 64, &Vs[cur ^ 1][w * 512]);
        }

        const bf16* K_ = Ks[cur];
        const bf16* V_ = Vs[cur];
        if (c <= ctw[1])
            attn_tiles<2>(K_, V_, qf, oA, oB, mOld, lSum, c, ctw, qabs, w, l31, hi, hi8, swzk);
        else if (c <= ctw[0])
            attn_tiles<1>(K_, V_, qf, oA, oB, mOld, lSum, c, ctw, qabs, w, l31, hi, hi8, swzk);
    }

#pragma unroll
    for (int qi = 0; qi < 2; ++qi) {
        const float inv = 1.f / lSum[qi];
        bf16* Op = O + (rowBase + qabs[qi]) * D_ + colBase;
#pragma unroll
        for (int g = 0; g < 4; ++g) {
            u32x2_t sA, sB;
            sA.x = pack2(oA[qi][4 * g + 0] * inv, oA[qi][4 * g + 1] * inv);
            sA.y = pack2(oA[qi][4 * g + 2] * inv, oA[qi][4 * g + 3] * inv);
            sB.x = pack2(oB[qi][4 * g + 0] * inv, oB[qi][4 * g + 1] * inv);
            sB.y = pack2(oB[qi][4 * g + 2] * inv, oB[qi][4 * g + 3] * inv);
            *(u32x2_t*)(Op + 8 * g + 4 * hi)      = sA;
            *(u32x2_t*)(Op + 32 + 8 * g + 4 * hi) = sB;
        }
    }
}

// ---------------------------------------------------------------- launch
extern "C" void kernel_launch(void* const* d_in, const int* in_sizes, int n_in,
                              void* d_out, int out_size, void* d_ws, size_t ws_size,
                              hipStream_t stream)
{
    (void)in_sizes; (void)n_in; (void)out_size; (void)ws_size;
    const float* x   = (const float*)d_in[0];
    const float* wq  = (const float*)d_in[1];
    const float* wk  = (const float*)d_in[2];
    const float* wv  = (const float*)d_in[3];
    const float* wo  = (const float*)d_in[4];
    const float* bo  = (const float*)d_in[5];
    const float* w1  = (const float*)d_in[6];
    const float* b1  = (const float*)d_in[7];
    const float* w2  = (const float*)d_in[8];
    const float* b2  = (const float*)d_in[9];
    const float* g1  = (const float*)d_in[10];
    const float* be1 = (const float*)d_in[11];
    const float* g2  = (const float*)d_in[12];
    const float* be2 = (const float*)d_in[13];
    float* out = (float*)d_out;

    char* ws = (char*)d_ws;
    const size_t SLOT = (size_t)8192 * 1024 * 2;   // 16MB
    bf16* xn     = (bf16*)(ws);
    bf16* attnb  = (bf16*)(ws);
    bf16* qkv    = (bf16*)(ws + SLOT);
    bf16* xn2    = (bf16*)(ws + SLOT);
    bf16* vtb    = (bf16*)(ws + 4 * SLOT);
    bf16* hidden = (bf16*)(ws + 2 * SLOT);
    float* x1    = (float*)(ws + 6 * SLOT);
    char* wpos   = ws + 6 * SLOT + (size_t)33554432;
    bf16* wqkvT = (bf16*)(wpos);
    bf16* woT = (bf16*)(wpos + (size_t)3 * 2097152);
    bf16* w1T = (bf16*)(wpos + (size_t)4 * 2097152);
    bf16* w2T = (bf16*)(wpos + (size_t)4 * 2097152 + 8388608);

    transpose_all<<<12288, 256, 0, stream>>>(wq, wk, wv, wo, w1, w2, wqkvT, woT, w1T, w2T);

    ln_k<<<8192, 256, 0, stream>>>(x, g1, be1, xn);

    // QKV: gemm2 (768 blocks = 3 full CU rounds, no tail)
    gemm2<0, 0, 0, 1><<<768, 512, 0, stream>>>(xn, wqkvT, nullptr, nullptr, qkv, 8192, 3072, 1024);

    vhead_transpose<<<8192, 256, 0, stream>>>(qkv, vtb);

    attn_flash<<<dim3(4, 64), 512, 0, stream>>>(qkv, vtb, attnb);

    gemm2<1, 0, 1, 0><<<256, 512, 0, stream>>>(attnb, woT, bo, x, x1, 8192, 1024, 1024);

    ln_k<<<8192, 256, 0, stream>>>(x1, g2, be2, xn2);

    // FFN1: gemm8 (512 blocks = 2 full rounds)
    gemm8<1, 1, 0, 1><<<512, 512, 0, stream>>>(xn2, w1T, b1, nullptr, hidden, 8192, 4096, 1024);

    gemm2<1, 0, 1, 0><<<256, 512, 0, stream>>>(hidden, w2T, b2, x1, out, 8192, 1024, 4096);
}

// Round 10
// 493.176 us; speedup vs baseline: 1.1747x; 1.1747x over previous
//
#include <hip/hip_runtime.h>
#include <hip/hip_bf16.h>
#include <stdint.h>

typedef __hip_bfloat16 bf16;
typedef __attribute__((ext_vector_type(8))) short bf16x8_t;
typedef __attribute__((ext_vector_type(4))) float f32x4_t;
typedef __attribute__((ext_vector_type(16))) float f32x16_t;
typedef __attribute__((ext_vector_type(2))) unsigned int u32x2_t;

#define B_ 4
#define T_ 2048
#define D_ 1024
#define H_ 16
#define HS_ 64
#define QKV_LD 3072

// ---------------------------------------------------------------- helpers
__device__ __forceinline__ void gload_lds16(const void* g, void* l) {
    __builtin_amdgcn_global_load_lds(
        (const __attribute__((address_space(1))) unsigned int*)g,
        (__attribute__((address_space(3))) unsigned int*)l, 16, 0, 0);
}

__device__ __forceinline__ bf16x8_t ldsv8(const bf16* p) {
    return *(const bf16x8_t*)p;
}

__device__ __forceinline__ unsigned pack2(float a, float b) {
    union { bf16 h[2]; unsigned u; } t;
    t.h[0] = __float2bfloat16(a);
    t.h[1] = __float2bfloat16(b);
    return t.u;
}

__device__ __forceinline__ float tmax16(const f32x16_t& s) {
    float a = fmaxf(s[0], s[8]),  b = fmaxf(s[1], s[9]);
    float c = fmaxf(s[2], s[10]), d = fmaxf(s[3], s[11]);
    float e = fmaxf(s[4], s[12]), f = fmaxf(s[5], s[13]);
    float g = fmaxf(s[6], s[14]), h = fmaxf(s[7], s[15]);
    a = fmaxf(a, e); b = fmaxf(b, f); c = fmaxf(c, g); d = fmaxf(d, h);
    return fmaxf(fmaxf(a, c), fmaxf(b, d));
}

__device__ __forceinline__ float tsum16(const f32x16_t& s) {
    float a = s[0] + s[8],  b = s[1] + s[9];
    float c = s[2] + s[10], d = s[3] + s[11];
    float e = s[4] + s[12], f = s[5] + s[13];
    float g = s[6] + s[14], h = s[7] + s[15];
    a += e; b += f; c += g; d += h;
    return (a + c) + (b + d);
}

// ---------------------------------------------------------------- fused weight transpose fp32->bf16
__global__ __launch_bounds__(256) void transpose_all(
    const float* wq, const float* wk, const float* wv, const float* wo,
    const float* w1, const float* w2,
    bf16* wqkvT, bf16* woT, bf16* w1T, bf16* w2T)
{
    __shared__ float tile[32][33];
    int blk = blockIdx.x;
    const float* W; bf16* WT; int K, N;
    if (blk < 4096) {
        const int which = blk >> 10; blk &= 1023;
        W  = which == 0 ? wq : which == 1 ? wk : which == 2 ? wv : wo;
        WT = which == 3 ? woT : wqkvT + (size_t)which * 1024 * 1024;
        K = 1024; N = 1024;
    } else if (blk < 8192) {
        blk -= 4096; W = w1; WT = w1T; K = 1024; N = 4096;
    } else {
        blk -= 8192; W = w2; WT = w2T; K = 4096; N = 1024;
    }
    const int nbx = N >> 5;
    const int bx = blk % nbx;
    const int by = blk / nbx;
    const int n0 = bx << 5, k0 = by << 5;
    const int tx = threadIdx.x & 31, ty = threadIdx.x >> 5;
#pragma unroll
    for (int i = 0; i < 32; i += 8)
        tile[ty + i][tx] = W[(long)(k0 + ty + i) * N + n0 + tx];
    __syncthreads();
#pragma unroll
    for (int i = 0; i < 32; i += 8)
        WT[(long)(n0 + ty + i) * K + k0 + tx] = __float2bfloat16(tile[tx][ty + i]);
}

// ---------------------------------------------------------------- per-head V transpose (bf16)
__global__ __launch_bounds__(256) void vhead_transpose(
    const bf16* __restrict__ QKV, bf16* __restrict__ VT)
{
    __shared__ bf16 tile[32][33];
    int idx = blockIdx.x;
    const int tt  = idx & 63;   idx >>= 6;
    const int hst = idx & 1;    idx >>= 1;
    const int bh  = idx;
    const int b = bh >> 4, h = bh & 15;
    const int tx = threadIdx.x & 31, ty = threadIdx.x >> 5;
    const long vrow = (long)b * T_ + tt * 32;
    const int  vcol = 2048 + h * HS_ + hst * 32;
#pragma unroll
    for (int i = 0; i < 32; i += 8)
        tile[ty + i][tx] = QKV[(vrow + ty + i) * QKV_LD + vcol + tx];
    __syncthreads();
    const long orow = (long)bh * HS_ + hst * 32;
#pragma unroll
    for (int i = 0; i < 32; i += 8)
        VT[(orow + ty + i) * T_ + tt * 32 + tx] = tile[tx][ty + i];
}

// ---------------------------------------------------------------- LayerNorm (fp32 in -> bf16 out)
__global__ __launch_bounds__(256) void ln_k(
    const float* __restrict__ x, const float* __restrict__ g,
    const float* __restrict__ be, bf16* __restrict__ out)
{
    const long row = blockIdx.x;
    const int t = threadIdx.x;
    const float4 v = ((const float4*)(x + row * D_))[t];
    float s  = v.x + v.y + v.z + v.w;
    float s2 = v.x * v.x + v.y * v.y + v.z * v.z + v.w * v.w;
#pragma unroll
    for (int m = 1; m < 64; m <<= 1) {
        s  += __shfl_xor(s, m, 64);
        s2 += __shfl_xor(s2, m, 64);
    }
    __shared__ float red[8];
    const int wv = t >> 6, ln = t & 63;
    if (ln == 0) { red[wv] = s; red[4 + wv] = s2; }
    __syncthreads();
    s  = red[0] + red[1] + red[2] + red[3];
    s2 = red[4] + red[5] + red[6] + red[7];
    const float mu  = s * (1.f / (float)D_);
    const float var = s2 * (1.f / (float)D_) - mu * mu;
    const float rs  = rsqrtf(var + 1e-5f);
    const float4 gv = ((const float4*)g)[t];
    const float4 bv = ((const float4*)be)[t];
    union { bf16 h[4]; short4 s4; } u;
    u.h[0] = __float2bfloat16((v.x - mu) * rs * gv.x + bv.x);
    u.h[1] = __float2bfloat16((v.y - mu) * rs * gv.y + bv.y);
    u.h[2] = __float2bfloat16((v.z - mu) * rs * gv.z + bv.z);
    u.h[3] = __float2bfloat16((v.w - mu) * rs * gv.w + bv.w);
    ((short4*)(out + row * D_))[t] = u.s4;
}

// ---------------------------------------------------------------- GEMM v2b: 256x128 tile, 8 waves,
// BK=64 dbuf, counted vmcnt, split-lgkm two-stage MFMA.
template<int HAS_BIAS, int RELU, int HAS_RES, int OUT_BF16>
__global__ __launch_bounds__(512, 1) void gemm2(
    const bf16* __restrict__ A, const bf16* __restrict__ BT,
    const float* __restrict__ bias, const float* __restrict__ res,
    void* __restrict__ Cout, int M, int N, int K)
{
    __shared__ bf16 As[2][256 * 64];
    __shared__ bf16 Bs[2][128 * 64];
    const int tid  = threadIdx.x;
    const int w    = tid >> 6;
    const int lane = tid & 63;
    const int wm = w >> 1, wn = w & 1;
    const int nbn = N >> 7;
    const int cpx = gridDim.x >> 3;
    const int bid = (blockIdx.x & 7) * cpx + (blockIdx.x >> 3);
    const int bm = bid / nbn, bn = bid % nbn;
    const int row0 = bm << 8, col0 = bn << 7;

    const bf16* aS0; const bf16* aS1; const bf16* aS2; const bf16* aS3;
    const bf16* bS0; const bf16* bS1;
    {
        int f0 = tid,        r0 = f0 >> 3, c0 = ((f0 & 7) ^ (r0 & 7)) << 3;
        int f1 = 512 + tid,  r1 = f1 >> 3, c1 = ((f1 & 7) ^ (r1 & 7)) << 3;
        int f2 = 1024 + tid, r2 = f2 >> 3, c2 = ((f2 & 7) ^ (r2 & 7)) << 3;
        int f3 = 1536 + tid, r3 = f3 >> 3, c3 = ((f3 & 7) ^ (r3 & 7)) << 3;
        aS0 = A + (long)(row0 + r0) * K + c0;
        aS1 = A + (long)(row0 + r1) * K + c1;
        aS2 = A + (long)(row0 + r2) * K + c2;
        aS3 = A + (long)(row0 + r3) * K + c3;
        bS0 = BT + (long)(col0 + r0) * K + c0;
        bS1 = BT + (long)(col0 + r1) * K + c1;
    }
    const int wbase = w * 64;

#define STAGE2(buf, kt) do {                                             \
        const long ko_ = (long)(kt) * 64;                                \
        gload_lds16(aS0 + ko_, &As[buf][(0 * 512 + wbase) * 8]);         \
        gload_lds16(aS1 + ko_, &As[buf][(1 * 512 + wbase) * 8]);         \
        gload_lds16(aS2 + ko_, &As[buf][(2 * 512 + wbase) * 8]);         \
        gload_lds16(aS3 + ko_, &As[buf][(3 * 512 + wbase) * 8]);         \
        gload_lds16(bS0 + ko_, &Bs[buf][(0 * 512 + wbase) * 8]);         \
        gload_lds16(bS1 + ko_, &Bs[buf][(1 * 512 + wbase) * 8]);         \
    } while (0)

    f32x4_t acc[4][4] = {};
    const int fr = lane & 15;
    const int fq = lane >> 4;
    const int nt = K >> 6;

    STAGE2(0, 0);
    STAGE2(1, 1);

    for (int t = 0; t < nt; ++t) {
        const int cur = t & 1;
        if (t < nt - 1) asm volatile("s_waitcnt vmcnt(6)" ::: "memory");
        else            asm volatile("s_waitcnt vmcnt(0)" ::: "memory");
        __builtin_amdgcn_s_barrier();

        bf16x8_t a0[4], b0[4], a1[4], b1[4];
#pragma unroll
        for (int m = 0; m < 4; ++m) {
            const int r = wm * 64 + m * 16 + fr;
            a0[m] = ldsv8(&As[cur][r * 64 + ((fq ^ (r & 7)) << 3)]);
        }
#pragma unroll
        for (int n = 0; n < 4; ++n) {
            const int r = wn * 64 + n * 16 + fr;
            b0[n] = ldsv8(&Bs[cur][r * 64 + ((fq ^ (r & 7)) << 3)]);
        }
        __builtin_amdgcn_sched_barrier(0);   // pin group order for lgkmcnt(8)
#pragma unroll
        for (int m = 0; m < 4; ++m) {
            const int r = wm * 64 + m * 16 + fr;
            a1[m] = ldsv8(&As[cur][r * 64 + (((4 + fq) ^ (r & 7)) << 3)]);
        }
#pragma unroll
        for (int n = 0; n < 4; ++n) {
            const int r = wn * 64 + n * 16 + fr;
            b1[n] = ldsv8(&Bs[cur][r * 64 + (((4 + fq) ^ (r & 7)) << 3)]);
        }
        asm volatile("s_waitcnt lgkmcnt(8)" ::: "memory");   // ks0 group landed
        __builtin_amdgcn_sched_barrier(0);
        __builtin_amdgcn_s_setprio(1);
#pragma unroll
        for (int m = 0; m < 4; ++m)
#pragma unroll
            for (int n = 0; n < 4; ++n)
                acc[m][n] = __builtin_amdgcn_mfma_f32_16x16x32_bf16(a0[m], b0[n], acc[m][n], 0, 0, 0);
        __builtin_amdgcn_s_setprio(0);
        asm volatile("s_waitcnt lgkmcnt(0)" ::: "memory");
        __builtin_amdgcn_sched_barrier(0);
        __builtin_amdgcn_s_barrier();
        if (t + 2 < nt) STAGE2(cur, t + 2);
        __builtin_amdgcn_s_setprio(1);
#pragma unroll
        for (int m = 0; m < 4; ++m)
#pragma unroll
            for (int n = 0; n < 4; ++n)
                acc[m][n] = __builtin_amdgcn_mfma_f32_16x16x32_bf16(a1[m], b1[n], acc[m][n], 0, 0, 0);
        __builtin_amdgcn_s_setprio(0);
    }
#undef STAGE2

    const int orow = fq << 2;
#pragma unroll
    for (int m = 0; m < 4; ++m) {
        const int rbase = row0 + wm * 64 + m * 16 + orow;
#pragma unroll
        for (int n = 0; n < 4; ++n) {
            const int c = col0 + wn * 64 + n * 16 + fr;
            float bv = 0.f;
            if (HAS_BIAS) bv = bias[c];
#pragma unroll
            for (int r = 0; r < 4; ++r) {
                float v = acc[m][n][r] + bv;
                if (RELU) v = fmaxf(v, 0.f);
                if (HAS_RES) v += res[(long)(rbase + r) * N + c];
                if (OUT_BF16)
                    ((bf16*)Cout)[(long)(rbase + r) * N + c] = __float2bfloat16(v);
                else
                    ((float*)Cout)[(long)(rbase + r) * N + c] = v;
            }
        }
    }
}

// ---------------------------------------------------------------- GEMM v3b: 256x256, 8 waves,
// 4-phase/K-tile, counted vmcnt, register read-ahead, full-coverage swizzle.
template<int HAS_BIAS, int RELU, int HAS_RES, int OUT_BF16>
__global__ __launch_bounds__(512, 1) void gemm8(
    const bf16* __restrict__ A, const bf16* __restrict__ BT,
    const float* __restrict__ bias, const float* __restrict__ res,
    void* __restrict__ Cout, int M, int N, int K)
{
    __shared__ bf16 As[2][2][256 * 32];
    __shared__ bf16 Bs[2][2][256 * 32];

    const int tid  = threadIdx.x;
    const int w    = tid >> 6;
    const int lane = tid & 63;
    const int wm = w >> 2, wn = w & 3;
    const int nbn = N >> 8;
    const int cpx = gridDim.x >> 3;
    const int bid = (blockIdx.x & 7) * cpx + (blockIdx.x >> 3);
    const int bm = bid / nbn, bn = bid % nbn;
    const int row0 = bm << 8, col0 = bn << 8;

    const int r0s = tid >> 2;
    const int c0s = (((tid & 3) ^ ((r0s ^ (r0s >> 2)) & 3)) << 3);
    const bf16* aU0 = A  + (long)(row0 + r0s) * K + c0s;
    const bf16* aU1 = aU0 + (long)128 * K;
    const bf16* bU0 = BT + (long)(col0 + r0s) * K + c0s;
    const bf16* bU1 = bU0 + (long)128 * K;
    const int wb8 = w * 512;

#define STAGE_A8(buf, kh, kt) do {                                        \
        const long ko_ = (long)(kt) * 64 + (kh) * 32;                     \
        gload_lds16(aU0 + ko_, &As[buf][kh][wb8]);                        \
        gload_lds16(aU1 + ko_, &As[buf][kh][4096 + wb8]);                 \
    } while (0)
#define STAGE_B8(buf, kh, kt) do {                                        \
        const long ko_ = (long)(kt) * 64 + (kh) * 32;                     \
        gload_lds16(bU0 + ko_, &Bs[buf][kh][wb8]);                        \
        gload_lds16(bU1 + ko_, &Bs[buf][kh][4096 + wb8]);                 \
    } while (0)

    f32x4_t acc[8][4] = {};
    bf16x8_t afA[8], afB[8], b01[2], b23[2], b01b[2], b23b[2];
    const int fr = lane & 15;
    const int fq = lane >> 4;
    const int nt = K >> 6;

#define SWZ8(rr) ((fq ^ ((rr ^ (rr >> 2)) & 3)) << 3)
#define RD_A8(dst, cur, ks) do { _Pragma("unroll")                         \
        for (int m = 0; m < 8; ++m) {                                      \
            const int rr = wm * 128 + m * 16 + fr;                         \
            dst[m] = ldsv8(&As[cur][ks][rr * 32 + SWZ8(rr)]);              \
        } } while (0)
#define RD_B8(dst, cur, ks, n0) do {                                       \
        { const int rr = wn * 64 + (n0) * 16 + fr;                         \
          dst[0] = ldsv8(&Bs[cur][ks][rr * 32 + SWZ8(rr)]); }              \
        { const int rr = wn * 64 + ((n0) + 1) * 16 + fr;                   \
          dst[1] = ldsv8(&Bs[cur][ks][rr * 32 + SWZ8(rr)]); }              \
    } while (0)
#define MM8(afx, bp, n0) do { _Pragma("unroll")                            \
        for (int m = 0; m < 8; ++m) {                                      \
            acc[m][n0]     = __builtin_amdgcn_mfma_f32_16x16x32_bf16(afx[m], bp[0], acc[m][n0],     0, 0, 0); \
            acc[m][(n0)+1] = __builtin_amdgcn_mfma_f32_16x16x32_bf16(afx[m], bp[1], acc[m][(n0)+1], 0, 0, 0); \
        } } while (0)
#define LGKM0_ do { asm volatile("s_waitcnt lgkmcnt(0)" ::: "memory");     \
                    __builtin_amdgcn_sched_barrier(0); } while (0)
#define SBAR_  __builtin_amdgcn_s_barrier()
#define PIN_   __builtin_amdgcn_sched_barrier(0)

    STAGE_A8(0, 0, 0);
    STAGE_B8(0, 0, 0);
    STAGE_A8(0, 1, 0);
    STAGE_B8(0, 1, 0);
    asm volatile("s_waitcnt vmcnt(4)" ::: "memory");
    SBAR_;

    for (int t = 0; t < nt - 1; ++t) {
        const int cur = t & 1, nb = cur ^ 1;
        RD_A8(afA, cur, 0); RD_B8(b01, cur, 0, 0);
        STAGE_A8(nb, 0, t + 1);
        SBAR_;
        LGKM0_;
        __builtin_amdgcn_s_setprio(1);
        RD_B8(b23, cur, 0, 2); PIN_;
        MM8(afA, b01, 0);
        __builtin_amdgcn_s_setprio(0);
        SBAR_;
        STAGE_B8(nb, 0, t + 1);
        asm volatile("s_waitcnt vmcnt(4)" ::: "memory");
        SBAR_;
        LGKM0_;
        __builtin_amdgcn_s_setprio(1);
        RD_A8(afB, cur, 1); RD_B8(b01b, cur, 1, 0); PIN_;
        MM8(afA, b23, 2);
        __builtin_amdgcn_s_setprio(0);
        SBAR_;
        STAGE_A8(nb, 1, t + 1);
        SBAR_;
        LGKM0_;
        __builtin_amdgcn_s_setprio(1);
        RD_B8(b23b, cur, 1, 2); PIN_;
        MM8(afB, b01b, 0);
        __builtin_amdgcn_s_setprio(0);
        SBAR_;
        STAGE_B8(nb, 1, t + 1);
        SBAR_;
        LGKM0_;
        __builtin_amdgcn_s_setprio(1);
        MM8(afB, b23b, 2);
        __builtin_amdgcn_s_setprio(0);
        asm volatile("s_waitcnt vmcnt(4)" ::: "memory");
        SBAR_;
    }
    {
        const int cur = (nt - 1) & 1;
        RD_A8(afA, cur, 0); RD_B8(b01, cur, 0, 0);
        SBAR_;
        LGKM0_;
        __builtin_amdgcn_s_setprio(1);
        RD_B8(b23, cur, 0, 2); PIN_;
        MM8(afA, b01, 0);
        __builtin_amdgcn_s_setprio(0);
        SBAR_;
        asm volatile("s_waitcnt vmcnt(0)" ::: "memory");
        SBAR_;
        LGKM0_;
        __builtin_amdgcn_s_setprio(1);
        RD_A8(afB, cur, 1); RD_B8(b01b, cur, 1, 0); PIN_;
        MM8(afA, b23, 2);
        __builtin_amdgcn_s_setprio(0);
        SBAR_;
        SBAR_;
        LGKM0_;
        __builtin_amdgcn_s_setprio(1);
        RD_B8(b23b, cur, 1, 2); PIN_;
        MM8(afB, b01b, 0);
        __builtin_amdgcn_s_setprio(0);
        SBAR_;
        LGKM0_;
        MM8(afB, b23b, 2);
    }
#undef STAGE_A8
#undef STAGE_B8
#undef SWZ8
#undef RD_A8
#undef RD_B8
#undef MM8
#undef LGKM0_
#undef SBAR_
#undef PIN_

    const int orow = fq << 2;
#pragma unroll
    for (int m = 0; m < 8; ++m) {
        const int rbase = row0 + wm * 128 + m * 16 + orow;
#pragma unroll
        for (int n = 0; n < 4; ++n) {
            const int c = col0 + wn * 64 + n * 16 + fr;
            float bv = 0.f;
            if (HAS_BIAS) bv = bias[c];
#pragma unroll
            for (int r = 0; r < 4; ++r) {
                float v = acc[m][n][r] + bv;
                if (RELU) v = fmaxf(v, 0.f);
                if (HAS_RES) v += res[(long)(rbase + r) * N + c];
                if (OUT_BF16)
                    ((bf16*)Cout)[(long)(rbase + r) * N + c] = __float2bfloat16(v);
                else
                    ((float*)Cout)[(long)(rbase + r) * N + c] = v;
            }
        }
    }
}

// ---------------------------------------------------------------- attention tile compute
// (round-6 structure: called once per q-tile so temporaries die between calls)
__device__ __forceinline__ void attn_tile(
    const bf16* K_, const bf16* V_, const bf16x8_t (&qf)[4],
    f32x16_t& oA, f32x16_t& oB, float& mOld, float& lSum,
    int c, int ct_w, int qabs, int w, int l31, int hi, int hi8, int swzk)
{
    const float kE  = 0.0450842200278f;   // (1/32) * log2(e)
    const float THR = 256.0f;             // defer-max threshold (e^8 bound)
    const bool diag = (c == ct_w);
    const bool two  = !(diag && !(w & 1));

    f32x16_t s0 = {}, s1 = {};
    __builtin_amdgcn_s_setprio(1);
#pragma unroll
    for (int s = 0; s < 4; ++s) {
        bf16x8_t kf = ldsv8(K_ + l31 * 64 + ((16 * s + hi8) ^ swzk));
        s0 = __builtin_amdgcn_mfma_f32_32x32x16_bf16(kf, qf[s], s0, 0, 0, 0);
    }
    if (two) {
#pragma unroll
        for (int s = 0; s < 4; ++s) {
            bf16x8_t kf = ldsv8(K_ + (32 + l31) * 64 + ((16 * s + hi8) ^ swzk));
            s1 = __builtin_amdgcn_mfma_f32_32x32x16_bf16(kf, qf[s], s1, 0, 0, 0);
        }
    }
    __builtin_amdgcn_s_setprio(0);

    if (diag) {
        const int stm = w & 1;
        const int kb0 = c * 64 + stm * 32 + 4 * hi;
        if (stm) {
#pragma unroll
            for (int r = 0; r < 16; ++r)
                if (kb0 + (r & 3) + 8 * (r >> 2) > qabs) s1[r] = -1e30f;
        } else {
#pragma unroll
            for (int r = 0; r < 16; ++r)
                if (kb0 + (r & 3) + 8 * (r >> 2) > qabs) s0[r] = -1e30f;
        }
    }

    float rm = tmax16(s0);
    if (two) rm = fmaxf(rm, tmax16(s1));
    {
        u32x2_t rr = __builtin_amdgcn_permlane32_swap(
            __float_as_uint(rm), __float_as_uint(rm), false, false);
        rm = fmaxf(__uint_as_float(rr.x), __uint_as_float(rr.y));
    }
    if (!__all(rm <= mOld + THR)) {   // T13 defer-max
        const float mN = fmaxf(mOld, rm);
        const float corr = exp2f((mOld - mN) * kE);
#pragma unroll
        for (int r = 0; r < 16; ++r) { oA[r] *= corr; oB[r] *= corr; }
        lSum *= corr;
        mOld = mN;
    }
    const float nmk = -mOld * kE;
#pragma unroll
    for (int r = 0; r < 16; ++r) s0[r] = exp2f(fmaf(s0[r], kE, nmk));
    if (two) {
#pragma unroll
        for (int r = 0; r < 16; ++r) s1[r] = exp2f(fmaf(s1[r], kE, nmk));
    }
    float rs = tsum16(s0);
    if (two) rs += tsum16(s1);
    {
        u32x2_t rr = __builtin_amdgcn_permlane32_swap(
            __float_as_uint(rs), __float_as_uint(rs), false, false);
        rs = __uint_as_float(rr.x) + __uint_as_float(rr.y);
    }
    lSum += rs;

    {
        unsigned pk_[8];
#pragma unroll
        for (int i = 0; i < 8; ++i) pk_[i] = pack2(s0[2 * i], s0[2 * i + 1]);
        union { unsigned u[4]; bf16x8_t v; } W0, W1;
        u32x2_t ra = __builtin_amdgcn_permlane32_swap(pk_[0], pk_[2], false, false);
        u32x2_t rb = __builtin_amdgcn_permlane32_swap(pk_[1], pk_[3], false, false);
        W0.u[0] = ra.x; W0.u[1] = rb.x; W0.u[2] = ra.y; W0.u[3] = rb.y;
        u32x2_t rc = __builtin_amdgcn_permlane32_swap(pk_[4], pk_[6], false, false);
        u32x2_t rd = __builtin_amdgcn_permlane32_swap(pk_[5], pk_[7], false, false);
        W1.u[0] = rc.x; W1.u[1] = rd.x; W1.u[2] = rc.y; W1.u[3] = rd.y;
        __builtin_amdgcn_s_setprio(1);
#pragma unroll
        for (int m = 0; m < 2; ++m) {
            const int kcol = 16 * m + hi8;
            bf16x8_t vf0 = ldsv8(V_ + l31 * 64 + (kcol ^ swzk));
            oA = __builtin_amdgcn_mfma_f32_32x32x16_bf16(vf0, m ? W1.v : W0.v, oA, 0, 0, 0);
            bf16x8_t vf1 = ldsv8(V_ + (32 + l31) * 64 + (kcol ^ swzk));
            oB = __builtin_amdgcn_mfma_f32_32x32x16_bf16(vf1, m ? W1.v : W0.v, oB, 0, 0, 0);
        }
        __builtin_amdgcn_s_setprio(0);
    }
    if (two) {
        unsigned pk_[8];
#pragma unroll
        for (int i = 0; i < 8; ++i) pk_[i] = pack2(s1[2 * i], s1[2 * i + 1]);
        union { unsigned u[4]; bf16x8_t v; } W0, W1;
        u32x2_t ra = __builtin_amdgcn_permlane32_swap(pk_[0], pk_[2], false, false);
        u32x2_t rb = __builtin_amdgcn_permlane32_swap(pk_[1], pk_[3], false, false);
        W0.u[0] = ra.x; W0.u[1] = rb.x; W0.u[2] = ra.y; W0.u[3] = rb.y;
        u32x2_t rc = __builtin_amdgcn_permlane32_swap(pk_[4], pk_[6], false, false);
        u32x2_t rd = __builtin_amdgcn_permlane32_swap(pk_[5], pk_[7], false, false);
        W1.u[0] = rc.x; W1.u[1] = rd.x; W1.u[2] = rc.y; W1.u[3] = rd.y;
        __builtin_amdgcn_s_setprio(1);
#pragma unroll
        for (int m = 0; m < 2; ++m) {
            const int kcol = 16 * (2 + m) + hi8;
            bf16x8_t vf0 = ldsv8(V_ + l31 * 64 + (kcol ^ swzk));
            oA = __builtin_amdgcn_mfma_f32_32x32x16_bf16(vf0, m ? W1.v : W0.v, oA, 0, 0, 0);
            bf16x8_t vf1 = ldsv8(V_ + (32 + l31) * 64 + (kcol ^ swzk));
            oB = __builtin_amdgcn_mfma_f32_32x32x16_bf16(vf1, m ? W1.v : W0.v, oB, 0, 0, 0);
        }
        __builtin_amdgcn_s_setprio(0);
    }
}

// ---------------------------------------------------------------- flash attention (causal) v5
// Complementary q-tile pairing: block bx owns q-tiles qLo=bx, qHi=7-bx (perfect
// balance), grid (4,64)=256=1/CU, shared KV stream, sequential attn_tile calls.
__global__ __launch_bounds__(512, 1) void attn_flash(
    const bf16* __restrict__ QKV, const bf16* __restrict__ VT,
    bf16* __restrict__ O)
{
    __shared__ bf16 Ks[2][64 * 64];
    __shared__ bf16 Vs[2][64 * 64];

    const int tid = threadIdx.x;
    const int w   = tid >> 6;
    const int ln  = tid & 63;
    const int l31 = ln & 31;
    const int hi  = ln >> 5;
    const int hi8 = hi << 3;

    const int qLo = blockIdx.x;        // 0..3
    const int qHi = 7 - qLo;           // 7..4
    const int bh = blockIdx.y;
    const long rowBase = (long)(bh >> 4) * T_;
    const int colBase = (bh & 15) * HS_;

    const int qabsL = qLo * 256 + w * 32 + l31;
    const int qabsH = qHi * 256 + w * 32 + l31;
    const int ct_L  = qLo * 4 + (w >> 1);
    const int ct_H  = qHi * 4 + (w >> 1);
    const int ctb   = qHi * 4 + 3;

    bf16x8_t qfL[4], qfH[4];
    {
        const bf16* qpL = QKV + (rowBase + qabsL) * QKV_LD + colBase + hi8;
        const bf16* qpH = QKV + (rowBase + qabsH) * QKV_LD + colBase + hi8;
#pragma unroll
        for (int s = 0; s < 4; ++s) {
            qfL[s] = *(const bf16x8_t*)(qpL + 16 * s);
            qfH[s] = *(const bf16x8_t*)(qpH + 16 * s);
        }
    }

    f32x16_t oLA = {}, oLB = {}, oHA = {}, oHB = {};
    float mL = -1e30f, lL = 0.f, mH = -1e30f, lH = 0.f;

    const int srow = tid >> 3;
    const int schunk = (((tid & 7) ^ (srow & 7)) << 3);
    const bf16* kSrc = QKV + (rowBase + srow) * QKV_LD + 1024 + colBase + schunk;
    const bf16* vSrc = VT + ((long)bh * HS_ + srow) * T_ + schunk;

    gload_lds16(kSrc, &Ks[0][w * 512]);
    gload_lds16(vSrc, &Vs[0][w * 512]);

    const int swzk = (l31 & 7) << 3;

    for (int c = 0; c <= ctb; ++c) {
        const int cur = c & 1;
        __syncthreads();

        if (c < ctb) {
            gload_lds16(kSrc + (long)(c + 1) * 64 * QKV_LD, &Ks[cur ^ 1][w * 512]);
            gload_lds16(vSrc + (c + 1) * 64, &Vs[cur ^ 1][w * 512]);
        }

        const bf16* K_ = Ks[cur];
        const bf16* V_ = Vs[cur];
        if (c <= ct_H)
            attn_tile(K_, V_, qfH, oHA, oHB, mH, lH, c, ct_H, qabsH, w, l31, hi, hi8, swzk);
        if (c <= ct_L)
            attn_tile(K_, V_, qfL, oLA, oLB, mL, lL, c, ct_L, qabsL, w, l31, hi, hi8, swzk);
    }

    {
        const float inv = 1.f / lH;
        bf16* Op = O + (rowBase + qabsH) * D_ + colBase;
#pragma unroll
        for (int g = 0; g < 4; ++g) {
            u32x2_t sA, sB;
            sA.x = pack2(oHA[4 * g + 0] * inv, oHA[4 * g + 1] * inv);
            sA.y = pack2(oHA[4 * g + 2] * inv, oHA[4 * g + 3] * inv);
            sB.x = pack2(oHB[4 * g + 0] * inv, oHB[4 * g + 1] * inv);
            sB.y = pack2(oHB[4 * g + 2] * inv, oHB[4 * g + 3] * inv);
            *(u32x2_t*)(Op + 8 * g + 4 * hi)      = sA;
            *(u32x2_t*)(Op + 32 + 8 * g + 4 * hi) = sB;
        }
    }
    {
        const float inv = 1.f / lL;
        bf16* Op = O + (rowBase + qabsL) * D_ + colBase;
#pragma unroll
        for (int g = 0; g < 4; ++g) {
            u32x2_t sA, sB;
            sA.x = pack2(oLA[4 * g + 0] * inv, oLA[4 * g + 1] * inv);
            sA.y = pack2(oLA[4 * g + 2] * inv, oLA[4 * g + 3] * inv);
            sB.x = pack2(oLB[4 * g + 0] * inv, oLB[4 * g + 1] * inv);
            sB.y = pack2(oLB[4 * g + 2] * inv, oLB[4 * g + 3] * inv);
            *(u32x2_t*)(Op + 8 * g + 4 * hi)      = sA;
            *(u32x2_t*)(Op + 32 + 8 * g + 4 * hi) = sB;
        }
    }
}

// ---------------------------------------------------------------- launch
extern "C" void kernel_launch(void* const* d_in, const int* in_sizes, int n_in,
                              void* d_out, int out_size, void* d_ws, size_t ws_size,
                              hipStream_t stream)
{
    (void)in_sizes; (void)n_in; (void)out_size; (void)ws_size;
    const float* x   = (const float*)d_in[0];
    const float* wq  = (const float*)d_in[1];
    const float* wk  = (const float*)d_in[2];
    const float* wv  = (const float*)d_in[3];
    const float* wo  = (const float*)d_in[4];
    const float* bo  = (const float*)d_in[5];
    const float* w1  = (const float*)d_in[6];
    const float* b1  = (const float*)d_in[7];
    const float* w2  = (const float*)d_in[8];
    const float* b2  = (const float*)d_in[9];
    const float* g1  = (const float*)d_in[10];
    const float* be1 = (const float*)d_in[11];
    const float* g2  = (const float*)d_in[12];
    const float* be2 = (const float*)d_in[13];
    float* out = (float*)d_out;

    char* ws = (char*)d_ws;
    const size_t SLOT = (size_t)8192 * 1024 * 2;   // 16MB
    bf16* xn     = (bf16*)(ws);
    bf16* attnb  = (bf16*)(ws);
    bf16* qkv    = (bf16*)(ws + SLOT);
    bf16* xn2    = (bf16*)(ws + SLOT);
    bf16* vtb    = (bf16*)(ws + 4 * SLOT);
    bf16* hidden = (bf16*)(ws + 2 * SLOT);
    float* x1    = (float*)(ws + 6 * SLOT);
    char* wpos   = ws + 6 * SLOT + (size_t)33554432;
    bf16* wqkvT = (bf16*)(wpos);
    bf16* woT = (bf16*)(wpos + (size_t)3 * 2097152);
    bf16* w1T = (bf16*)(wpos + (size_t)4 * 2097152);
    bf16* w2T = (bf16*)(wpos + (size_t)4 * 2097152 + 8388608);

    transpose_all<<<12288, 256, 0, stream>>>(wq, wk, wv, wo, w1, w2, wqkvT, woT, w1T, w2T);

    ln_k<<<8192, 256, 0, stream>>>(x, g1, be1, xn);

    // QKV: gemm2 (768 blocks = 3 full CU rounds)
    gemm2<0, 0, 0, 1><<<768, 512, 0, stream>>>(xn, wqkvT, nullptr, nullptr, qkv, 8192, 3072, 1024);

    vhead_transpose<<<8192, 256, 0, stream>>>(qkv, vtb);

    attn_flash<<<dim3(4, 64), 512, 0, stream>>>(qkv, vtb, attnb);

    gemm2<1, 0, 1, 0><<<256, 512, 0, stream>>>(attnb, woT, bo, x, x1, 8192, 1024, 1024);

    ln_k<<<8192, 256, 0, stream>>>(x1, g2, be2, xn2);

    // FFN1: gemm8 (512 blocks = 2 full rounds)
    gemm8<1, 1, 0, 1><<<512, 512, 0, stream>>>(xn2, w1T, b1, nullptr, hidden, 8192, 4096, 1024);

    gemm2<1, 0, 1, 0><<<256, 512, 0, stream>>>(hidden, w2T, b2, x1, out, 8192, 1024, 4096);
}